// Round 8
// baseline (257.185 us; speedup 1.0000x reference)
//
#include <hip/hip_runtime.h>
#include <math.h>

#define BB 256
#define LL 500
#define EE 300
#define NROWS (BB * LL)      // 128000
#define ND 18                // dot vectors: aw3 r0-2, cw3, aw5 r0-4, cw5, aw7 r0-6, cw7
#define KSTEPS 10            // 10 x 32 = 320 >= 300 (tail zero-padded in W)
#define WPB2 32              // waves per batch in dots kernel (32 x 16 rows = 512 >= 500)
#define LPAD 512             // padded rows per batch in dws
#define DSLOT 20             // d-slots per batch in dws (18 used)

// ---------------------------------------------------------------------------
// R14: pure-GEMM ingest + split epilogue. R13's result closed the case on
// compute structure: scalar-LDS (R6/R8/R12, ~6k cyc issue/wave), scalar-SGPR
// (R10), and MFMA-no-barrier (R13, ~2k cyc) ALL land at 77-90us -- wall time
// is insensitive to 3x changes in issue work. The invariant is x ingested at
// ~1.7 TB/s effective at <=5 waves/SIMD, vs 6.3 TB/s for the full-occupancy
// streaming ubench. Hypothesis A: latency-bound (occupancy x outstanding too
// low). This kernel maximizes TLP: wave = 16 rows (16x16x32 MFMA, fp32 via
// 2-term bf16 split), NO halo (dots -> d-major workspace, epilogue split to
// a 2nd trivial kernel), no LDS, no barriers, no cross-lane; ~65 VGPR ->
// 7-8 waves/SIMD x 2048 blocks. Per-lane reads are one contiguous 32 B run;
// C-store is coalesced float4 (C/D rows = 4 consecutive l). 18 > 16 output
// cols -> second B-group (cols 16-17 real, rest zero). k-tail 300..319 via
// address clamp only: dummy A x zero W = 0, no masking. If this still runs
// ~90us at >50% occupancy, hypothesis B (pattern-dependent read-rate
// ceiling) is proven and we're at the floor.
// ---------------------------------------------------------------------------

typedef short  bf16x8 __attribute__((ext_vector_type(8)));
typedef float  f32x4  __attribute__((ext_vector_type(4)));

// prepass: per-lane B fragments for 16x16x32, hi/lo bf16 split, 2 col-groups.
// uint4 slot g at wf4[(s*64+lane)*4+g]: g0=G0hi g1=G0lo g2=G1hi g3=G1lo.
// dword qq in slot: elems e=0,1 -> k = s*32 + (lane>>4)*8 + qq*2 + e;
// col c = lane&15; d = (g<2) ? c : 16+c.
__global__ void wfrag16_build(
    const float* __restrict__ aw3, const float* __restrict__ aw5,
    const float* __restrict__ aw7, const float* __restrict__ cw3,
    const float* __restrict__ cw5, const float* __restrict__ cw7,
    unsigned int* __restrict__ wf)
{
    const int idx = blockIdx.x * 256 + threadIdx.x;   // dword index 0..10239
    if (idx >= KSTEPS * 64 * 16) return;
    const int s    = idx >> 10;
    const int lane = (idx >> 4) & 63;
    const int w    = idx & 15;
    const int g    = w >> 2;
    const int qq   = w & 3;
    const int c    = lane & 15;
    const int d    = (g < 2) ? c : 16 + c;
    const bool hiPart = ((g & 1) == 0);

    unsigned int outw = 0;
#pragma unroll
    for (int e = 0; e < 2; ++e) {
        const int k = s * 32 + ((lane >> 4) * 8) + qq * 2 + e;
        float wv = 0.0f;
        if (d < ND && k < EE) {
            if      (d < 3)  wv = aw3[d * EE + k];
            else if (d == 3) wv = cw3[k];
            else if (d < 9)  wv = aw5[(d - 4) * EE + k];
            else if (d == 9) wv = cw5[k];
            else if (d < 17) wv = aw7[(d - 10) * EE + k];
            else             wv = cw7[k];
        }
        const unsigned int u = __float_as_uint(wv);
        unsigned short h;
        if (hiPart) {
            h = (unsigned short)(u >> 16);
        } else {
            const float whi = __uint_as_float(u & 0xFFFF0000u);
            const float lo  = wv - whi;
            h = (unsigned short)(__float_as_uint(lo) >> 16);
        }
        outw |= ((unsigned int)h) << (16 * e);
    }
    wf[idx] = outw;
}

// dots kernel: wave = 16 rows of one batch; dws[b][d][LPAD] d-major.
__global__ __launch_bounds__(256) void dots_kernel(
    const float* __restrict__ x, const unsigned int* __restrict__ wf,
    float* __restrict__ dws)
{
    const int tid  = threadIdx.x;
    const int wav  = blockIdx.x * 4 + (tid >> 6);   // 0..8191
    const int lane = tid & 63;
    const int b    = wav >> 5;                      // batch
    const int j    = wav & 31;                      // 16-row tile in batch
    const int l0   = j * 16;

    const int row = lane & 15;
    const int q8  = (lane >> 4) * 8;                // k-offset within step

    int gl = l0 + row; gl = gl > LL - 1 ? LL - 1 : gl;   // rows 500..511 dup
    const float* xr = x + ((size_t)b * LL + gl) * EE;

    const uint4* wf4 = (const uint4*)wf;

    // prologue: step-0 A loads (one contiguous 32 B per lane)
    float4 xa = *(const float4*)(xr + q8);
    float4 xb = *(const float4*)(xr + q8 + 4);

    f32x4 accA = {0.f, 0.f, 0.f, 0.f};
    f32x4 accB = {0.f, 0.f, 0.f, 0.f};

#pragma unroll 1
    for (int s = 0; s < KSTEPS; ++s) {
        // next-step A loads in flight under this step's cvt+MFMA.
        // tail clamp: offsets capped at 296 -> max float read = 299 (in-row);
        // the dummy data multiplies zero W (k>=300) -> exact zero contribution.
        float4 xa_n, xb_n;
        if (s + 1 < KSTEPS) {
            const int o  = (s + 1) * 32 + q8;
            const int oa = o     > 296 ? 296 : o;
            const int ob = o + 4 > 296 ? 296 : o + 4;
            xa_n = *(const float4*)(xr + oa);
            xb_n = *(const float4*)(xr + ob);
        }

        // W fragments (L2-hot 40 KB, shared by all 8192 waves): 64 B/lane
        const uint4 g0h = wf4[(s * 64 + lane) * 4 + 0];
        const uint4 g0l = wf4[(s * 64 + lane) * 4 + 1];
        const uint4 g1h = wf4[(s * 64 + lane) * 4 + 2];
        const uint4 g1l = wf4[(s * 64 + lane) * 4 + 3];

        // fp32 -> bf16 hi/lo split (covers the W L2 latency with VALU)
        bf16x8 ahi, alo;
        const float xf[8] = {xa.x, xa.y, xa.z, xa.w, xb.x, xb.y, xb.z, xb.w};
#pragma unroll
        for (int e = 0; e < 8; ++e) {
            const unsigned int u = __float_as_uint(xf[e]);
            ahi[e] = (short)(u >> 16);
            const float hif = __uint_as_float(u & 0xFFFF0000u);
            const float lo  = xf[e] - hif;
            alo[e] = (short)(__float_as_uint(lo) >> 16);
        }

        const bf16x8 b0h = __builtin_bit_cast(bf16x8, g0h);
        const bf16x8 b0l = __builtin_bit_cast(bf16x8, g0l);
        const bf16x8 b1h = __builtin_bit_cast(bf16x8, g1h);
        const bf16x8 b1l = __builtin_bit_cast(bf16x8, g1l);

        // D = Xhi*Whi + Xhi*Wlo + Xlo*Whi per col-group
        accA = __builtin_amdgcn_mfma_f32_16x16x32_bf16(ahi, b0h, accA, 0, 0, 0);
        accA = __builtin_amdgcn_mfma_f32_16x16x32_bf16(ahi, b0l, accA, 0, 0, 0);
        accA = __builtin_amdgcn_mfma_f32_16x16x32_bf16(alo, b0h, accA, 0, 0, 0);
        accB = __builtin_amdgcn_mfma_f32_16x16x32_bf16(ahi, b1h, accB, 0, 0, 0);
        accB = __builtin_amdgcn_mfma_f32_16x16x32_bf16(ahi, b1l, accB, 0, 0, 0);
        accB = __builtin_amdgcn_mfma_f32_16x16x32_bf16(alo, b1h, accB, 0, 0, 0);

        if (s + 1 < KSTEPS) { xa = xa_n; xb = xb_n; }
    }

    // C/D (m89/m91-verified): col = lane&15, row = (lane>>4)*4 + reg ->
    // each lane holds 4 CONSECUTIVE l -> one coalesced float4 store.
    const int lrow = l0 + (lane >> 4) * 4;
    {
        const int d = lane & 15;
        float* dst = dws + ((size_t)b * DSLOT + d) * LPAD + lrow;
        *(float4*)dst = __builtin_bit_cast(float4, accA);
    }
    if ((lane & 15) < 2) {
        const int d = 16 + (lane & 15);
        float* dst = dws + ((size_t)b * DSLOT + d) * LPAD + lrow;
        *(float4*)dst = __builtin_bit_cast(float4, accB);
    }
}

// epilogue: thread = output row; d-major dws reads are coalesced per tap.
__global__ __launch_bounds__(256) void epi_kernel(
    const float* __restrict__ dws,
    const float* __restrict__ ab3, const float* __restrict__ cb3,
    const float* __restrict__ ab5, const float* __restrict__ cb5,
    const float* __restrict__ ab7, const float* __restrict__ cb7,
    float* __restrict__ out)
{
    const int r = blockIdx.x * 256 + threadIdx.x;
    if (r >= NROWS) return;
    const int b = r / LL;
    const int l = r - b * LL;
    const float* db = dws + (size_t)b * DSLOT * LPAD;

    {   // k=3: taps d=0..2 at l-1..l+1, center d=3
        float pre = 0.0f;
#pragma unroll
        for (int tp = 0; tp < 3; ++tp) {
            const int lp = l + tp - 1;
            if (lp >= 0 && lp < LL) pre += db[tp * LPAD + lp];
        }
        const float sg = 1.0f / (1.0f + expf(-(pre + ab3[0])));
        out[r] = tanhf(sg * db[3 * LPAD + l] + cb3[0]);
    }
    {   // k=5: taps d=4..8 at l-2..l+2, center d=9
        float pre = 0.0f;
#pragma unroll
        for (int tp = 0; tp < 5; ++tp) {
            const int lp = l + tp - 2;
            if (lp >= 0 && lp < LL) pre += db[(4 + tp) * LPAD + lp];
        }
        const float sg = 1.0f / (1.0f + expf(-(pre + ab5[0])));
        out[NROWS + r] = tanhf(sg * db[9 * LPAD + l] + cb5[0]);
    }
    {   // k=7: taps d=10..16 at l-3..l+3, center d=17
        float pre = 0.0f;
#pragma unroll
        for (int tp = 0; tp < 7; ++tp) {
            const int lp = l + tp - 3;
            if (lp >= 0 && lp < LL) pre += db[(10 + tp) * LPAD + lp];
        }
        const float sg = 1.0f / (1.0f + expf(-(pre + ab7[0])));
        out[2 * NROWS + r] = tanhf(sg * db[17 * LPAD + l] + cb7[0]);
    }
}

extern "C" void kernel_launch(void* const* d_in, const int* in_sizes, int n_in,
                              void* d_out, int out_size, void* d_ws, size_t ws_size,
                              hipStream_t stream) {
    const float* x   = (const float*)d_in[0];
    const float* aw3 = (const float*)d_in[1];
    const float* ab3 = (const float*)d_in[2];
    const float* cw3 = (const float*)d_in[3];
    const float* cb3 = (const float*)d_in[4];
    const float* aw5 = (const float*)d_in[5];
    const float* ab5 = (const float*)d_in[6];
    const float* cw5 = (const float*)d_in[7];
    const float* cb5 = (const float*)d_in[8];
    const float* aw7 = (const float*)d_in[9];
    const float* ab7 = (const float*)d_in[10];
    const float* cw7 = (const float*)d_in[11];
    const float* cb7 = (const float*)d_in[12];

    // workspace layout: wf (40 KB) | dws 256x20x512 floats (10.5 MB)
    unsigned int* wf  = (unsigned int*)d_ws;
    float*        dws = (float*)((char*)d_ws + 65536);
    float*        out = (float*)d_out;   // [out3 | out5 | out7]

    wfrag16_build<<<40, 256, 0, stream>>>(aw3, aw5, aw7, cw3, cw5, cw7, wf);

    // 8192 wave-jobs (256 batches x 32 tiles), 4 independent waves/block
    dots_kernel<<<2048, 256, 0, stream>>>(x, wf, dws);

    // 128000 outputs
    epi_kernel<<<500, 256, 0, stream>>>(dws, ab3, cb3, ab5, cb5, ab7, cb7, out);
}